// Round 8
// baseline (27.457 us; speedup 1.0000x reference)
//
#include <hip/hip_runtime.h>
#include <math.h>

#define N_ROWS 8192
#define D 16
#define TILE 128
#define NT 64            /* 8192/128 */
#define NPAIR 1056       /* sum over rows of ceil((NT-it)/2) */

/* workspace layout (bytes) */
#define OFF_PT   0            /* float pt[1056] */
#define OFF_PS   8192         /* float ps[1056] */

typedef short  bf16x8 __attribute__((ext_vector_type(8)));
typedef float  f32x4  __attribute__((ext_vector_type(4)));

#if __has_builtin(__builtin_amdgcn_sqrtf)
#define SQRTF(x) __builtin_amdgcn_sqrtf(x)
#else
#define SQRTF(x) sqrtf(x)
#endif

/* codon index -> biosynthetic family id (K resolves to aspartate; '*' -> -1)
   families: 0=glutamate 1=aspartate 2=serine 3=pyruvate 4=aromatic 5=histidine */
__device__ __constant__ signed char FAM_LUT[64] = {
  4,4,3,3, 3,3,3,3,   /* UUU..CUG: F F L L L L L L */
  1,1,1,1, 3,3,3,3,   /* AUU..GUG: I I I M V V V V */
  2,2,2,2, 0,0,0,0,   /* UCU..CCG: S S S S P P P P */
  1,1,1,1, 3,3,3,3,   /* ACU..GCG: T T T T A A A A */
  4,4,-1,-1, 5,5,0,0, /* UAU..CAG: Y Y * * H H Q Q */
  1,1,1,1, 1,1,0,0,   /* AAU..GAG: N N K K D D E E */
  2,2,-1,4, 0,0,0,0,  /* UGU..CGG: C C * W R R R R */
  2,2,0,0, 2,2,2,2    /* AGU..GGG: S S R R G G G G */
};

__device__ __forceinline__ unsigned short f2bf(float f) {   /* RNE, finite inputs */
  unsigned u = __float_as_uint(f);
  u += 0x7fffu + ((u >> 16) & 1u);
  return (unsigned short)(u >> 16);
}
__device__ __forceinline__ float bf2f(unsigned short s) {
  return __uint_as_float((unsigned)s << 16);
}
/* S(m) = sum_{n=1..m} ceil(n/2) */
__device__ __forceinline__ int S_of(int m) {
  return (m & 1) ? (((m + 1) * (m + 1)) >> 2) : ((m * (m + 2)) >> 2);
}

__global__ __launch_bounds__(512, 4) void pair_kernel(
    const float* __restrict__ emb, const int* __restrict__ idx,
    float* __restrict__ pt, float* __restrict__ ps) {
  /* flat block -> (it, pair p): row it=NT-m owns pairs (it+2p, it+2p+1) */
  const int b = blockIdx.x;
  const int cc = NPAIR - b;                       /* in [1, NPAIR] */
  int m = (int)(2.0f * sqrtf((float)cc));
  if (m > NT) m = NT;
  if (m < 1) m = 1;
  while (S_of(m) < cc) ++m;
  while (m > 1 && S_of(m - 1) >= cc) --m;
  const int it  = NT - m;
  const int p   = b - (NPAIR - S_of(m));
  const int jt0 = it + 2 * p;
  const int jt1 = jt0 + 1;
  const bool v1 = (jt1 < NT);

  /* B tiles in MFMA fragment-linear order: [tile][mj][half][lr] x 16B chunks */
  __shared__ __align__(16) unsigned short BH[4096];  /* 8KB: 2 tiles hi */
  __shared__ __align__(16) unsigned short BL[4096];  /* 8KB: 2 tiles lo */
  __shared__ float2 SFJ[256];    /* x = sq_j, y = fam_j (None=-2, invalid=-3) */
  __shared__ float  SQI[TILE];   /* sq_i */
  __shared__ float  FAI[TILE];   /* fam_i (None=-1) */
  __shared__ float  rT[8], rS[8];

  const int t  = threadIdx.x;
  const int w  = t >> 6;          /* wave 0..7: i-strip w */
  const int l  = t & 63;
  const int lr = l & 15;          /* fragment row/col index */
  const int g  = l >> 4;          /* k-slice group 0..3 */
  const int half = g & 1;         /* dims 0-7 vs 8-15 */

  /* (a) per-row scalars: t<128 -> i-side, t in [128,384) -> j-side (2 tiles) */
  if (t < 384) {
    const bool iside = (t < 128);
    const int  local = iside ? t : (t - 128);          /* i: 0..127, j: 0..255 */
    bool valid = true;
    int row;
    if (iside) row = it * TILE + local;
    else {
      const int jtile = (local < 128) ? jt0 : jt1;
      valid = (jtile < NT);
      row = min(jtile, NT - 1) * TILE + (local & 127);
    }
    const float4* s4 = (const float4*)(emb + (size_t)row * D);
    float4 a0 = s4[0], a1 = s4[1], a2 = s4[2], a3 = s4[3];
    float v[16];
    v[0]=a0.x; v[1]=a0.y; v[2]=a0.z; v[3]=a0.w;
    v[4]=a1.x; v[5]=a1.y; v[6]=a1.z; v[7]=a1.w;
    v[8]=a2.x; v[9]=a2.y; v[10]=a2.z; v[11]=a2.w;
    v[12]=a3.x; v[13]=a3.y; v[14]=a3.z; v[15]=a3.w;
    float ss = v[0] * v[0];
#pragma unroll
    for (int k = 1; k < 16; ++k) ss = fmaf(v[k], v[k], ss);
    const int f = FAM_LUT[idx[row] & 63];
    if (iside) { SQI[local] = ss; FAI[local] = (f >= 0) ? (float)f : -1.0f; }
    else {
      SFJ[local] = make_float2(valid ? ss : 0.0f,
                               valid ? ((f >= 0) ? (float)f : -2.0f) : -3.0f);
    }
  }

  /* (b) B staging: all 512 threads, one 16B chunk each (t>>8 = tile) */
  {
    const int ti = t >> 8, c8 = t & 255;
    const int mjs = c8 >> 5, hs = (c8 >> 4) & 1, lrs = c8 & 15;
    const int jtile = ti ? jt1 : jt0;
    const bool valid = (jtile < NT);
    const int row = min(jtile, NT - 1) * TILE + mjs * 16 + lrs;
    const float4* s4 = (const float4*)(emb + (size_t)row * D + hs * 8);
    float4 b0 = s4[0], b1 = s4[1];
    float vb[8];
    vb[0]=b0.x; vb[1]=b0.y; vb[2]=b0.z; vb[3]=b0.w;
    vb[4]=b1.x; vb[5]=b1.y; vb[6]=b1.z; vb[7]=b1.w;
    unsigned short h8[8], l8[8];
#pragma unroll
    for (int k = 0; k < 8; ++k) {
      const unsigned short h = f2bf(vb[k]);
      h8[k] = valid ? h : (unsigned short)0;
      l8[k] = valid ? f2bf(vb[k] - bf2f(h)) : (unsigned short)0;
    }
    *(bf16x8*)(BH + t * 8) = *(bf16x8*)h8;
    *(bf16x8*)(BL + t * 8) = *(bf16x8*)l8;
  }

  /* (c) A fragment, PRE-SCALED by -2 ([hi|lo] along K=32) */
  const int arow = it * TILE + w * 16 + lr;
  const float4* a4 = (const float4*)(emb + (size_t)arow * D + half * 8);
  float4 c0 = a4[0], c1 = a4[1];
  float va[8];
  va[0]=c0.x; va[1]=c0.y; va[2]=c0.z; va[3]=c0.w;
  va[4]=c1.x; va[5]=c1.y; va[6]=c1.z; va[7]=c1.w;
  unsigned short f8[8];
#pragma unroll
  for (int k = 0; k < 8; ++k) {
    const float sv = -2.0f * va[k];                 /* exact scaling */
    const unsigned short h = f2bf(sv);
    f8[k] = (g < 2) ? h : f2bf(sv - bf2f(h));
  }
  const bf16x8 afrag = *(bf16x8*)f8;

  __syncthreads();

  float sqi[4], fai[4];
#pragma unroll
  for (int r = 0; r < 4; ++r) {
    sqi[r] = SQI[w * 16 + g * 4 + r];   /* C/D row = g*4+r */
    fai[r] = FAI[w * 16 + g * 4 + r];
  }

  const int bofs = (half * 16 + lr) * 8;   /* ushort offset within an mj-group */
  float tT0 = 0.0f, tS0 = 0.0f, tT1 = 0.0f, tS1 = 0.0f;
#pragma unroll
  for (int mj = 0; mj < 16; ++mj) {
    const int base = (mj >> 3) * 2048 + (mj & 7) * 256 + bofs;
    const bf16x8 bhi = *(const bf16x8*)(BH + base);
    const bf16x8 blo = *(const bf16x8*)(BL + base);
    const float2 sfj = SFJ[mj * 16 + lr];            /* C/D col = lr */
    /* acc starts at sqi+sqj; A is -2*a -> after 2 MFMAs acc == d2 */
    f32x4 acc = { sqi[0] + sfj.x, sqi[1] + sfj.x, sqi[2] + sfj.x, sqi[3] + sfj.x };
    acc = __builtin_amdgcn_mfma_f32_16x16x32_bf16(afrag, blo, acc, 0, 0, 0);
    acc = __builtin_amdgcn_mfma_f32_16x16x32_bf16(afrag, bhi, acc, 0, 0, 0);
#pragma unroll
    for (int r = 0; r < 4; ++r) {
      const float d2   = fmaxf(acc[r], 0.0f);
      const float dist = SQRTF(d2);
      const float sm   = (fai[r] == sfj.y) ? dist : 0.0f;
      if (mj < 8) { tT0 += dist; tS0 += sm; }
      else        { tT1 += dist; tS1 += sm; }
    }
  }

  /* per-tile weights, then block reduction */
  const float w0 = (jt0 == it) ? 1.0f : 2.0f;
  const float w1 = v1 ? 2.0f : 0.0f;
  float accT = fmaf(w0, tT0, w1 * tT1);
  float accS = fmaf(w0, tS0, w1 * tS1);
#pragma unroll
  for (int off = 32; off > 0; off >>= 1) {
    accT += __shfl_down(accT, off);
    accS += __shfl_down(accS, off);
  }
  if (l == 0) { rT[w] = accT; rS[w] = accS; }
  __syncthreads();
  if (t == 0) {
    float sT = 0.0f, sS = 0.0f;
#pragma unroll
    for (int k = 0; k < 8; ++k) { sT += rT[k]; sS += rS[k]; }
    pt[b] = sT;
    ps[b] = sS;
  }
}

__global__ __launch_bounds__(512) void final_kernel(
    const float* __restrict__ pt, const float* __restrict__ ps,
    const int* __restrict__ idx, float* __restrict__ out) {
  const int t = threadIdx.x, w = t >> 6, l = t & 63;
  __shared__ float  HW[8][8];    /* per-wave family counts */
  __shared__ double rTd[8], rSd[8];

  /* ballot histogram: no atomics, 8192 items over 8 waves x 16 rounds */
  float myCnt = 0.0f;            /* lane f (<6) counts family f */
#pragma unroll
  for (int rr = 0; rr < 16; ++rr) {
    const int f = FAM_LUT[idx[rr * 512 + t] & 63];
#pragma unroll
    for (int fam = 0; fam < 6; ++fam) {
      const unsigned long long mk = __ballot(f == fam);
      if (l == fam) myCnt += (float)__popcll(mk);
    }
  }
  if (l < 8) HW[w][l] = (l < 6) ? myCnt : 0.0f;

  double sT = 0.0, sS = 0.0;
  for (int k = t; k < NPAIR; k += 512) { sT += (double)pt[k]; sS += (double)ps[k]; }
#pragma unroll
  for (int off = 32; off > 0; off >>= 1) {
    sT += __shfl_down(sT, off);
    sS += __shfl_down(sS, off);
  }
  if (l == 0) { rTd[w] = sT; rSd[w] = sS; }
  __syncthreads();
  if (t == 0) {
    double tot = 0.0, sam = 0.0;
#pragma unroll
    for (int k = 0; k < 8; ++k) { tot += rTd[k]; sam += rSd[k]; }
    double same_sum = 0.0;
    for (int f = 0; f < 6; ++f) {
      double c = 0.0;
      for (int k = 0; k < 8; ++k) c += (double)HW[k][f];
      same_sum += c * c;
    }
    const double total  = (double)N_ROWS * (double)N_ROWS;
    const double same_d = sam / (same_sum + 1e-10);
    const double diff_d = (tot - sam) / (total - same_sum + 1e-10);
    double loss = same_d - 0.5 * diff_d + 1.0;
    out[0] = (float)(loss > 0.0 ? loss : 0.0);
  }
}

extern "C" void kernel_launch(void* const* d_in, const int* in_sizes, int n_in,
                              void* d_out, int out_size, void* d_ws, size_t ws_size,
                              hipStream_t stream) {
  const float* emb = (const float*)d_in[0];
  const int*   idx = (const int*)d_in[1];
  char* ws = (char*)d_ws;
  float* pt = (float*)(ws + OFF_PT);
  float* ps = (float*)(ws + OFF_PS);

  pair_kernel<<<dim3(NPAIR), dim3(512), 0, stream>>>(emb, idx, pt, ps);
  final_kernel<<<dim3(1), dim3(512), 0, stream>>>(pt, ps, idx, (float*)d_out);
}